// Round 2
// baseline (338.201 us; speedup 1.0000x reference)
//
#include <hip/hip_runtime.h>

typedef unsigned short ushort_t;
typedef __attribute__((ext_vector_type(8))) short short8;
typedef __attribute__((ext_vector_type(4))) float f32x4;

#define BK 32

// ---- bf16 helpers (RNE) ----
__device__ __forceinline__ ushort_t f2bf(float x) {
  union { float f; unsigned u; } v; v.f = x;
  unsigned r = v.u + 0x7fffu + ((v.u >> 16) & 1u);
  return (ushort_t)(r >> 16);
}
__device__ __forceinline__ float bf2f(ushort_t h) {
  union { unsigned u; float f; } v; v.u = ((unsigned)h) << 16;
  return v.f;
}

// ---- async global->LDS, 16B per lane, wave-uniform LDS base ----
__device__ __forceinline__ void async_cp16(const ushort_t* g, ushort_t* lds) {
  __builtin_amdgcn_global_load_lds(
      (const __attribute__((address_space(1))) unsigned int*)g,
      (__attribute__((address_space(3))) unsigned int*)lds, 16, 0, 0);
}

// =====================================================================
// NT GEMM core (m97 structure): C[m][n] = sum_k A[m][k]*B[n][k], bf16 in,
// fp32 acc. Tile 128x128, BK=32, 256 threads = 4 waves (2x2), each wave
// 4x4 MFMAs of 16x16x32.
// EPI 1: store bf16 C to Cb (ldc).  EPI 2: tan + dual f32 store Cf0,Cf1.
// =====================================================================
template <int EPI>
__device__ __forceinline__ void gemm_core(
    const ushort_t* __restrict__ A, int lda,
    const ushort_t* __restrict__ B, int ldb,
    int K,
    ushort_t* sA, ushort_t* sB,
    ushort_t* Cb, float* Cf0, float* Cf1, int ldc) {
  const int t = threadIdx.x;
  const int wave = t >> 6, lane = t & 63;
  const int lm = lane & 15, lq = lane >> 4;
  const int wr = wave >> 1, wc = wave & 1;

  f32x4 acc[4][4] = {};

  // staging: thread t loads 16B at row (t>>2), elem (t&3)*8 of the 128x32 tile
  const ushort_t* ga = A + (size_t)(t >> 2) * lda + (t & 3) * 8;
  const ushort_t* gb = B + (size_t)(t >> 2) * ldb + (t & 3) * 8;
  ushort_t* sA0 = sA + wave * 512;  // wave-uniform base
  ushort_t* sB0 = sB + wave * 512;

  for (int k0 = 0; k0 < K; k0 += BK) {
    async_cp16(ga + k0, sA0);                           // rows 0..63
    async_cp16(ga + k0 + (size_t)64 * lda, sA0 + 2048); // rows 64..127
    async_cp16(gb + k0, sB0);
    async_cp16(gb + k0 + (size_t)64 * ldb, sB0 + 2048);
    __syncthreads();  // drains vmcnt before s_barrier

    short8 af[4], bf4[4];
#pragma unroll
    for (int i = 0; i < 4; i++) {
      af[i]  = *(const short8*)(sA + ((wr * 64 + i * 16 + lm) * BK + lq * 8));
      bf4[i] = *(const short8*)(sB + ((wc * 64 + i * 16 + lm) * BK + lq * 8));
    }
#pragma unroll
    for (int mt = 0; mt < 4; mt++)
#pragma unroll
      for (int nt = 0; nt < 4; nt++)
        acc[mt][nt] = __builtin_amdgcn_mfma_f32_16x16x32_bf16(
            af[mt], bf4[nt], acc[mt][nt], 0, 0, 0);
    __syncthreads();
  }

  // C/D layout (verified m89/m91): col = lane&15, row = (lane>>4)*4 + reg
#pragma unroll
  for (int mt = 0; mt < 4; mt++) {
    int rb = wr * 64 + mt * 16 + lq * 4;
#pragma unroll
    for (int nt = 0; nt < 4; nt++) {
      int c = wc * 64 + nt * 16 + lm;
#pragma unroll
      for (int r = 0; r < 4; r++) {
        size_t idx = (size_t)(rb + r) * ldc + c;
        if (EPI == 1) {
          Cb[idx] = f2bf(acc[mt][nt][r]);
        } else {
          float v = __tanf(acc[mt][nt][r]);
          Cf0[idx] = v;
          Cf1[idx] = v;
        }
      }
    }
  }
}

// =====================================================================
// Pre-pass kernels: f32 -> bf16 conversion (+ transpose)
// =====================================================================

// elementwise f32 -> bf16, 4 elems/thread
__global__ __launch_bounds__(256) void conv_ew(
    const float* __restrict__ in, ushort_t* __restrict__ out, int n) {
  int i = (blockIdx.x * 256 + threadIdx.x) * 4;
  if (i < n) {
    float4 v = *(const float4*)(in + i);
    ushort4 o;
    o.x = f2bf(v.x); o.y = f2bf(v.y); o.z = f2bf(v.z); o.w = f2bf(v.w);
    *(ushort4*)(out + i) = o;
  }
}

// 64x64 tile: read f32, write bf16 straight (outn) + bf16 transposed (outt)
__global__ __launch_bounds__(256) void convT(
    const float* __restrict__ in, ushort_t* __restrict__ outn,
    ushort_t* __restrict__ outt, int n) {
  __shared__ float tile[64][65];
  const int t = threadIdx.x;
  const int r0 = blockIdx.y * 64, c0 = blockIdx.x * 64;
  const int cr = t >> 4;        // 0..15
  const int cc = (t & 15) * 4;  // 0..60
#pragma unroll
  for (int p = 0; p < 4; p++) {
    int r = cr + p * 16;
    float4 v = *(const float4*)(in + (size_t)(r0 + r) * n + c0 + cc);
    tile[r][cc + 0] = v.x; tile[r][cc + 1] = v.y;
    tile[r][cc + 2] = v.z; tile[r][cc + 3] = v.w;
    ushort4 o;
    o.x = f2bf(v.x); o.y = f2bf(v.y); o.z = f2bf(v.z); o.w = f2bf(v.w);
    *(ushort4*)(outn + (size_t)(r0 + r) * n + c0 + cc) = o;
  }
  __syncthreads();
#pragma unroll
  for (int p = 0; p < 4; p++) {
    int r = cr + p * 16;  // output row = c0 + r
    ushort4 o;
    o.x = f2bf(tile[cc + 0][r]); o.y = f2bf(tile[cc + 1][r]);
    o.z = f2bf(tile[cc + 2][r]); o.w = f2bf(tile[cc + 3][r]);
    *(ushort4*)(outt + (size_t)(c0 + r) * n + r0 + cc) = o;
  }
}

// =====================================================================
// GEMM kernels
// =====================================================================

// K1: pw_t[512 x 8192] = (concat(pre,cur) @ weight)^T via NT GEMM
__global__ __launch_bounds__(256) void k1_gemm(
    const ushort_t* __restrict__ wt_t, const ushort_t* __restrict__ pre,
    const ushort_t* __restrict__ cur, ushort_t* __restrict__ pw_t) {
  __shared__ __align__(16) ushort_t sA[128 * BK];
  __shared__ __align__(16) ushort_t sB[128 * BK];
  const int bm = blockIdx.x & 3, bn = blockIdx.x >> 2;
  const int n0 = bn * 128;
  const ushort_t* A = wt_t + (size_t)bm * 128 * 512;
  const ushort_t* B = (n0 < 4096) ? (pre + (size_t)n0 * 512)
                                  : (cur + (size_t)(n0 - 4096) * 512);
  ushort_t* C = pw_t + (size_t)bm * 128 * 8192 + n0;
  gemm_core<1>(A, 512, B, 512, 512, sA, sB, C, nullptr, nullptr, 8192);
}

// K2 fused: half0 pre_h = adj @ cur_w ; half1 cur_h = adj^T @ pre_w
__global__ __launch_bounds__(256) void k2_gemm(
    const ushort_t* __restrict__ adj, const ushort_t* __restrict__ adj_t,
    const ushort_t* __restrict__ pw_t, ushort_t* __restrict__ pn) {
  __shared__ __align__(16) ushort_t sA[128 * BK];
  __shared__ __align__(16) ushort_t sB[128 * BK];
  const int b = blockIdx.x;
  const int half = b >> 7, bb = b & 127;
  const int bm = bb & 31, bn = bb >> 5;
  const ushort_t* A = (half ? adj_t : adj) + (size_t)bm * 128 * 4096;
  const ushort_t* B = pw_t + (size_t)bn * 128 * 8192 + (half ? 0 : 4096);
  ushort_t* C = pn + (half ? (size_t)4096 * 512 : 0) +
                (size_t)bm * 128 * 512 + bn * 128;
  gemm_core<1>(A, 4096, B, 8192, 4096, sA, sB, C, nullptr, nullptr, 512);
}

// row L2-normalize in place: pn [8192 x 512] bf16, one wave per row
__global__ __launch_bounds__(256) void rownorm_kernel(ushort_t* __restrict__ pn) {
  const int t = threadIdx.x;
  const int wave = t >> 6, lane = t & 63;
  const size_t row = (size_t)blockIdx.x * 4 + wave;
  ushort_t* p = pn + row * 512 + lane * 8;
  short8 v = *(const short8*)p;
  float f[8];
  float s = 0.f;
#pragma unroll
  for (int i = 0; i < 8; i++) {
    f[i] = bf2f((ushort_t)v[i]);
    s += f[i] * f[i];
  }
#pragma unroll
  for (int off = 32; off > 0; off >>= 1) s += __shfl_xor(s, off, 64);
  float scale = 1.0f / fmaxf(sqrtf(s), 1e-8f);
  short8 o;
#pragma unroll
  for (int i = 0; i < 8; i++) o[i] = (short)f2bf(f[i] * scale);
  *(short8*)p = o;
}

// K3: cos = pre_n @ cur_n^T, tan, dual f32 store
__global__ __launch_bounds__(256) void k3_gemm(
    const ushort_t* __restrict__ pn, float* __restrict__ out) {
  __shared__ __align__(16) ushort_t sA[128 * BK];
  __shared__ __align__(16) ushort_t sB[128 * BK];
  const int bm = blockIdx.x & 31, bn = blockIdx.x >> 5;
  const ushort_t* A = pn + (size_t)bm * 128 * 512;
  const ushort_t* B = pn + (size_t)4096 * 512 + (size_t)bn * 128 * 512;
  float* C0 = out + (size_t)bm * 128 * 4096 + bn * 128;
  gemm_core<2>(A, 512, B, 512, 512, sA, sB, nullptr, C0,
               C0 + (size_t)4096 * 4096, 4096);
}

// =====================================================================
extern "C" void kernel_launch(void* const* d_in, const int* in_sizes, int n_in,
                              void* d_out, int out_size, void* d_ws,
                              size_t ws_size, hipStream_t stream) {
  const float* pre = (const float*)d_in[0];   // [4096,512] f32
  const float* cur = (const float*)d_in[1];   // [4096,512] f32
  const float* adj = (const float*)d_in[2];   // [4096,4096] f32
  const float* wt  = (const float*)d_in[3];   // [512,512] f32
  float* out = (float*)d_out;                 // 2 x [4096,4096] f32

  // workspace layout (bf16 buffers, ~93 MB)
  ushort_t* adj_bf = (ushort_t*)d_ws;                       // 4096*4096
  ushort_t* adj_t  = adj_bf + (size_t)4096 * 4096;          // 4096*4096
  ushort_t* pw_t   = adj_t + (size_t)4096 * 4096;           // 512*8192
  ushort_t* pn     = pw_t + (size_t)512 * 8192;             // 8192*512
  ushort_t* wt_t   = pn + (size_t)8192 * 512;               // 512*512
  ushort_t* wt_bf  = wt_t + (size_t)512 * 512;              // 512*512 (dummy)
  ushort_t* pre_bf = wt_bf + (size_t)512 * 512;             // 4096*512
  ushort_t* cur_bf = pre_bf + (size_t)4096 * 512;           // 4096*512

  conv_ew<<<2048, 256, 0, stream>>>(pre, pre_bf, 4096 * 512);
  conv_ew<<<2048, 256, 0, stream>>>(cur, cur_bf, 4096 * 512);
  convT<<<dim3(64, 64), 256, 0, stream>>>(adj, adj_bf, adj_t, 4096);
  convT<<<dim3(8, 8), 256, 0, stream>>>(wt, wt_bf, wt_t, 512);
  k1_gemm<<<256, 256, 0, stream>>>(wt_t, pre_bf, cur_bf, pw_t);
  k2_gemm<<<256, 256, 0, stream>>>(adj_bf, adj_t, pw_t, pn);
  rownorm_kernel<<<2048, 256, 0, stream>>>(pn);
  k3_gemm<<<1024, 256, 0, stream>>>(pn, out);
}

// Round 3
// 336.605 us; speedup vs baseline: 1.0047x; 1.0047x over previous
//
#include <hip/hip_runtime.h>

typedef unsigned short ushort_t;
typedef __attribute__((ext_vector_type(8))) short short8;
typedef __attribute__((ext_vector_type(4))) float f32x4;

#define BK 32

// ---- bf16 helpers (RNE) ----
__device__ __forceinline__ ushort_t f2bf(float x) {
  union { float f; unsigned u; } v; v.f = x;
  unsigned r = v.u + 0x7fffu + ((v.u >> 16) & 1u);
  return (ushort_t)(r >> 16);
}
__device__ __forceinline__ float bf2f(ushort_t h) {
  union { unsigned u; float f; } v; v.u = ((unsigned)h) << 16;
  return v.f;
}

// ---- async global->LDS, 16B per lane, wave-uniform LDS base ----
__device__ __forceinline__ void async_cp16(const ushort_t* g, ushort_t* lds) {
  __builtin_amdgcn_global_load_lds(
      (const __attribute__((address_space(1))) unsigned int*)g,
      (__attribute__((address_space(3))) unsigned int*)lds, 16, 0, 0);
}

// =====================================================================
// NT GEMM core: C[m][n] = sum_k A[m][k]*B[n][k], bf16 in, fp32 acc.
// Tile MT x NT (MT,NT in {64,128}), BK=32, 256 threads = 4 waves (2x2),
// each wave (MT/32)x(NT/32) MFMAs of 16x16x32.
// EPI 1: store bf16 C to Cb.  EPI 2: tan + dual f32 store Cf0,Cf1.
// =====================================================================
template <int MT, int NT, int EPI>
__device__ __forceinline__ void gemm_core(
    const ushort_t* __restrict__ A, int lda,
    const ushort_t* __restrict__ B, int ldb,
    int K,
    ushort_t* sA, ushort_t* sB,
    ushort_t* Cb, float* Cf0, float* Cf1, int ldc) {
  constexpr int MI = MT / 32, NI = NT / 32;
  const int t = threadIdx.x;
  const int wave = t >> 6, lane = t & 63;
  const int lm = lane & 15, lq = lane >> 4;
  const int wr = wave >> 1, wc = wave & 1;

  f32x4 acc[MI][NI] = {};

  // staging: thread t loads 16B at row (t>>2), elem (t&3)*8 of a 64x32 slab
  const ushort_t* ga = A + (size_t)(t >> 2) * lda + (t & 3) * 8;
  const ushort_t* gb = B + (size_t)(t >> 2) * ldb + (t & 3) * 8;
  ushort_t* sA0 = sA + wave * 512;  // wave-uniform base
  ushort_t* sB0 = sB + wave * 512;

  for (int k0 = 0; k0 < K; k0 += BK) {
    async_cp16(ga + k0, sA0);                                         // rows 0..63
    if (MT == 128) async_cp16(ga + k0 + (size_t)64 * lda, sA0 + 2048); // rows 64..127
    async_cp16(gb + k0, sB0);
    if (NT == 128) async_cp16(gb + k0 + (size_t)64 * ldb, sB0 + 2048);
    __syncthreads();  // drains vmcnt before s_barrier

    short8 af[MI], bf4[NI];
#pragma unroll
    for (int i = 0; i < MI; i++)
      af[i] = *(const short8*)(sA + ((wr * (MT / 2) + i * 16 + lm) * BK + lq * 8));
#pragma unroll
    for (int i = 0; i < NI; i++)
      bf4[i] = *(const short8*)(sB + ((wc * (NT / 2) + i * 16 + lm) * BK + lq * 8));
#pragma unroll
    for (int mt = 0; mt < MI; mt++)
#pragma unroll
      for (int nt = 0; nt < NI; nt++)
        acc[mt][nt] = __builtin_amdgcn_mfma_f32_16x16x32_bf16(
            af[mt], bf4[nt], acc[mt][nt], 0, 0, 0);
    __syncthreads();
  }

  // C/D layout (verified m89/m91): col = lane&15, row = (lane>>4)*4 + reg
#pragma unroll
  for (int mt = 0; mt < MI; mt++) {
    int rb = wr * (MT / 2) + mt * 16 + lq * 4;
#pragma unroll
    for (int nt = 0; nt < NI; nt++) {
      int c = wc * (NT / 2) + nt * 16 + lm;
#pragma unroll
      for (int r = 0; r < 4; r++) {
        size_t idx = (size_t)(rb + r) * ldc + c;
        if (EPI == 1) {
          Cb[idx] = f2bf(acc[mt][nt][r]);
        } else {
          float v = __tanf(acc[mt][nt][r]);
          Cf0[idx] = v;
          Cf1[idx] = v;
        }
      }
    }
  }
}

// =====================================================================
// Pre-pass kernels: f32 -> bf16 conversion (+ transpose)
// =====================================================================

// elementwise f32 -> bf16, 4 elems/thread
__global__ __launch_bounds__(256) void conv_ew(
    const float* __restrict__ in, ushort_t* __restrict__ out, int n) {
  int i = (blockIdx.x * 256 + threadIdx.x) * 4;
  if (i < n) {
    float4 v = *(const float4*)(in + i);
    ushort4 o;
    o.x = f2bf(v.x); o.y = f2bf(v.y); o.z = f2bf(v.z); o.w = f2bf(v.w);
    *(ushort4*)(out + i) = o;
  }
}

// 64x64 tile: read f32, write bf16 straight (outn) + bf16 transposed (outt)
__global__ __launch_bounds__(256) void convT(
    const float* __restrict__ in, ushort_t* __restrict__ outn,
    ushort_t* __restrict__ outt, int n) {
  __shared__ float tile[64][65];
  const int t = threadIdx.x;
  const int r0 = blockIdx.y * 64, c0 = blockIdx.x * 64;
  const int cr = t >> 4;        // 0..15
  const int cc = (t & 15) * 4;  // 0..60
#pragma unroll
  for (int p = 0; p < 4; p++) {
    int r = cr + p * 16;
    float4 v = *(const float4*)(in + (size_t)(r0 + r) * n + c0 + cc);
    tile[r][cc + 0] = v.x; tile[r][cc + 1] = v.y;
    tile[r][cc + 2] = v.z; tile[r][cc + 3] = v.w;
    ushort4 o;
    o.x = f2bf(v.x); o.y = f2bf(v.y); o.z = f2bf(v.z); o.w = f2bf(v.w);
    *(ushort4*)(outn + (size_t)(r0 + r) * n + c0 + cc) = o;
  }
  __syncthreads();
#pragma unroll
  for (int p = 0; p < 4; p++) {
    int r = cr + p * 16;  // output row = c0 + r
    ushort4 o;
    o.x = f2bf(tile[cc + 0][r]); o.y = f2bf(tile[cc + 1][r]);
    o.z = f2bf(tile[cc + 2][r]); o.w = f2bf(tile[cc + 3][r]);
    *(ushort4*)(outt + (size_t)(c0 + r) * n + r0 + cc) = o;
  }
}

// =====================================================================
// GEMM kernels
// =====================================================================

// K1: pw_t[512 x 8192] = (concat(pre,cur) @ weight)^T via NT GEMM
// 64x128 tiles, 512 blocks (2/CU). Same-XCD sequence (b, b+8, ...) shares
// the wt_t strip (bm fixed per 64-block stretch) automatically.
__global__ __launch_bounds__(256) void k1_gemm(
    const ushort_t* __restrict__ wt_t, const ushort_t* __restrict__ pre,
    const ushort_t* __restrict__ cur, ushort_t* __restrict__ pw_t) {
  __shared__ __align__(16) ushort_t sA[64 * BK];
  __shared__ __align__(16) ushort_t sB[128 * BK];
  const int bm = blockIdx.x & 7, bn = blockIdx.x >> 3;
  const int n0 = bn * 128;
  const ushort_t* A = wt_t + (size_t)bm * 64 * 512;
  const ushort_t* B = (n0 < 4096) ? (pre + (size_t)n0 * 512)
                                  : (cur + (size_t)(n0 - 4096) * 512);
  ushort_t* C = pw_t + (size_t)bm * 64 * 8192 + n0;
  gemm_core<64, 128, 1>(A, 512, B, 512, 512, sA, sB, C, nullptr, nullptr, 8192);
}

// K2 fused: half0 pre_h = adj @ cur_w ; half1 cur_h = adj^T @ pre_w
// 128x64 tiles, 512 blocks (2/CU). XCD swizzle: same-XCD consecutive
// blocks (stride 8) sweep bn 0..7 with bm fixed -> adj strip fetched
// once per XCD, reused 8x from L2.
__global__ __launch_bounds__(256) void k2_gemm(
    const ushort_t* __restrict__ adj, const ushort_t* __restrict__ adj_t,
    const ushort_t* __restrict__ pw_t, ushort_t* __restrict__ pn) {
  __shared__ __align__(16) ushort_t sA[128 * BK];
  __shared__ __align__(16) ushort_t sB[64 * BK];
  const int b = blockIdx.x;
  const int half = b >> 8, bb = b & 255;
  const int bn = (bb >> 3) & 7;
  const int bm = (bb & 7) | ((bb >> 6) << 3);
  const ushort_t* A = (half ? adj_t : adj) + (size_t)bm * 128 * 4096;
  const ushort_t* B = pw_t + (size_t)bn * 64 * 8192 + (half ? 0 : 4096);
  ushort_t* C = pn + (half ? (size_t)4096 * 512 : 0) +
                (size_t)bm * 128 * 512 + bn * 64;
  gemm_core<128, 64, 1>(A, 4096, B, 8192, 4096, sA, sB, C, nullptr, nullptr, 512);
}

// row L2-normalize in place: pn [8192 x 512] bf16, one wave per row
__global__ __launch_bounds__(256) void rownorm_kernel(ushort_t* __restrict__ pn) {
  const int t = threadIdx.x;
  const int wave = t >> 6, lane = t & 63;
  const size_t row = (size_t)blockIdx.x * 4 + wave;
  ushort_t* p = pn + row * 512 + lane * 8;
  short8 v = *(const short8*)p;
  float f[8];
  float s = 0.f;
#pragma unroll
  for (int i = 0; i < 8; i++) {
    f[i] = bf2f((ushort_t)v[i]);
    s += f[i] * f[i];
  }
#pragma unroll
  for (int off = 32; off > 0; off >>= 1) s += __shfl_xor(s, off, 64);
  float scale = 1.0f / fmaxf(sqrtf(s), 1e-8f);
  short8 o;
#pragma unroll
  for (int i = 0; i < 8; i++) o[i] = (short)f2bf(f[i] * scale);
  *(short8*)p = o;
}

// K3: cos = pre_n @ cur_n^T, tan, dual f32 store. 1024 blocks (4 rounds).
__global__ __launch_bounds__(256) void k3_gemm(
    const ushort_t* __restrict__ pn, float* __restrict__ out) {
  __shared__ __align__(16) ushort_t sA[128 * BK];
  __shared__ __align__(16) ushort_t sB[128 * BK];
  const int bm = blockIdx.x & 31, bn = blockIdx.x >> 5;
  const ushort_t* A = pn + (size_t)bm * 128 * 512;
  const ushort_t* B = pn + (size_t)4096 * 512 + (size_t)bn * 128 * 512;
  float* C0 = out + (size_t)bm * 128 * 4096 + bn * 128;
  gemm_core<128, 128, 2>(A, 512, B, 512, 512, sA, sB, nullptr, C0,
                         C0 + (size_t)4096 * 4096, 4096);
}

// =====================================================================
extern "C" void kernel_launch(void* const* d_in, const int* in_sizes, int n_in,
                              void* d_out, int out_size, void* d_ws,
                              size_t ws_size, hipStream_t stream) {
  const float* pre = (const float*)d_in[0];   // [4096,512] f32
  const float* cur = (const float*)d_in[1];   // [4096,512] f32
  const float* adj = (const float*)d_in[2];   // [4096,4096] f32
  const float* wt  = (const float*)d_in[3];   // [512,512] f32
  float* out = (float*)d_out;                 // 2 x [4096,4096] f32

  // workspace layout (bf16 buffers, ~93 MB)
  ushort_t* adj_bf = (ushort_t*)d_ws;                       // 4096*4096
  ushort_t* adj_t  = adj_bf + (size_t)4096 * 4096;          // 4096*4096
  ushort_t* pw_t   = adj_t + (size_t)4096 * 4096;           // 512*8192
  ushort_t* pn     = pw_t + (size_t)512 * 8192;             // 8192*512
  ushort_t* wt_t   = pn + (size_t)8192 * 512;               // 512*512
  ushort_t* wt_bf  = wt_t + (size_t)512 * 512;              // 512*512 (dummy)
  ushort_t* pre_bf = wt_bf + (size_t)512 * 512;             // 4096*512
  ushort_t* cur_bf = pre_bf + (size_t)4096 * 512;           // 4096*512

  conv_ew<<<2048, 256, 0, stream>>>(pre, pre_bf, 4096 * 512);
  conv_ew<<<2048, 256, 0, stream>>>(cur, cur_bf, 4096 * 512);
  convT<<<dim3(64, 64), 256, 0, stream>>>(adj, adj_bf, adj_t, 4096);
  convT<<<dim3(8, 8), 256, 0, stream>>>(wt, wt_bf, wt_t, 512);
  k1_gemm<<<512, 256, 0, stream>>>(wt_t, pre_bf, cur_bf, pw_t);
  k2_gemm<<<512, 256, 0, stream>>>(adj_bf, adj_t, pw_t, pn);
  rownorm_kernel<<<2048, 256, 0, stream>>>(pn);
  k3_gemm<<<1024, 256, 0, stream>>>(pn, out);
}

// Round 4
// 333.602 us; speedup vs baseline: 1.0138x; 1.0090x over previous
//
#include <hip/hip_runtime.h>

typedef unsigned short ushort_t;
typedef __attribute__((ext_vector_type(8))) short short8;
typedef __attribute__((ext_vector_type(4))) float f32x4;

// ---- bf16 helpers (RNE) ----
__device__ __forceinline__ ushort_t f2bf(float x) {
  union { float f; unsigned u; } v; v.f = x;
  unsigned r = v.u + 0x7fffu + ((v.u >> 16) & 1u);
  return (ushort_t)(r >> 16);
}
__device__ __forceinline__ float bf2f(ushort_t h) {
  union { unsigned u; float f; } v; v.u = ((unsigned)h) << 16;
  return v.f;
}

// ---- async global->LDS, 16B per lane, wave-uniform LDS base ----
__device__ __forceinline__ void async_cp16(const ushort_t* g, ushort_t* lds) {
  __builtin_amdgcn_global_load_lds(
      (const __attribute__((address_space(1))) unsigned int*)g,
      (__attribute__((address_space(3))) unsigned int*)lds, 16, 0, 0);
}

// =====================================================================
// NT GEMM core: C[m][n] = sum_k A[m][k]*B[n][k], bf16 in, fp32 acc.
// Tile MT x NT, K-chunk BKT (32 or 64), 256 threads = 4 waves (2x2).
// EPI 1: store bf16 C to Cb.
// EPI 2: v = tan(acc * ip[row] * ic[col]); dual f32 store Cf0, Cf1.
// =====================================================================
template <int MT, int NT, int BKT, int EPI>
__device__ __forceinline__ void gemm_core(
    const ushort_t* __restrict__ A, int lda,
    const ushort_t* __restrict__ B, int ldb,
    int K,
    ushort_t* sA, ushort_t* sB,
    ushort_t* Cb, float* Cf0, float* Cf1, int ldc,
    const float* __restrict__ ip, const float* __restrict__ ic) {
  constexpr int MI = MT / 32, NI = NT / 32, KU = BKT / 32;
  constexpr int LPR = BKT / 8;    // lanes per staged row
  constexpr int RPC = 256 / LPR;  // rows per cp16 call
  const int t = threadIdx.x;
  const int wave = t >> 6, lane = t & 63;
  const int lm = lane & 15, lq = lane >> 4;
  const int wr = wave >> 1, wc = wave & 1;

  f32x4 acc[MI][NI] = {};

  const ushort_t* ga = A + (size_t)(t / LPR) * lda + (t % LPR) * 8;
  const ushort_t* gb = B + (size_t)(t / LPR) * ldb + (t % LPR) * 8;
  ushort_t* sA0 = sA + wave * 512;  // wave-uniform base; lane-linear t*8
  ushort_t* sB0 = sB + wave * 512;

  for (int k0 = 0; k0 < K; k0 += BKT) {
#pragma unroll
    for (int j = 0; j < MT / RPC; j++)
      async_cp16(ga + k0 + (size_t)j * RPC * lda, sA0 + j * 2048);
#pragma unroll
    for (int j = 0; j < NT / RPC; j++)
      async_cp16(gb + k0 + (size_t)j * RPC * ldb, sB0 + j * 2048);
    __syncthreads();  // drains vmcnt before s_barrier

#pragma unroll
    for (int ku = 0; ku < KU; ku++) {
      short8 af[MI], bf4[NI];
#pragma unroll
      for (int i = 0; i < MI; i++)
        af[i] = *(const short8*)(sA + (wr * (MT / 2) + i * 16 + lm) * BKT +
                                 ku * 32 + lq * 8);
#pragma unroll
      for (int i = 0; i < NI; i++)
        bf4[i] = *(const short8*)(sB + (wc * (NT / 2) + i * 16 + lm) * BKT +
                                  ku * 32 + lq * 8);
#pragma unroll
      for (int mt = 0; mt < MI; mt++)
#pragma unroll
        for (int nt = 0; nt < NI; nt++)
          acc[mt][nt] = __builtin_amdgcn_mfma_f32_16x16x32_bf16(
              af[mt], bf4[nt], acc[mt][nt], 0, 0, 0);
    }
    __syncthreads();
  }

  // C/D layout (verified m89/m91): col = lane&15, row = (lane>>4)*4 + reg
#pragma unroll
  for (int mt = 0; mt < MI; mt++) {
    int rb = wr * (MT / 2) + mt * 16 + lq * 4;
#pragma unroll
    for (int nt = 0; nt < NI; nt++) {
      int c = wc * (NT / 2) + nt * 16 + lm;
#pragma unroll
      for (int r = 0; r < 4; r++) {
        size_t idx = (size_t)(rb + r) * ldc + c;
        if (EPI == 1) {
          Cb[idx] = f2bf(acc[mt][nt][r]);
        } else {
          float v = __tanf(acc[mt][nt][r] * ip[rb + r] * ic[c]);
          Cf0[idx] = v;
          Cf1[idx] = v;
        }
      }
    }
  }
}

// =====================================================================
// convT: 64x64 tile, read f32, write bf16 straight + bf16 transposed
// =====================================================================
__global__ __launch_bounds__(256) void convT(
    const float* __restrict__ in, ushort_t* __restrict__ outn,
    ushort_t* __restrict__ outt, int n) {
  __shared__ float tile[64][65];
  const int t = threadIdx.x;
  const int r0 = blockIdx.y * 64, c0 = blockIdx.x * 64;
  const int cr = t >> 4;        // 0..15
  const int cc = (t & 15) * 4;  // 0..60
#pragma unroll
  for (int p = 0; p < 4; p++) {
    int r = cr + p * 16;
    float4 v = *(const float4*)(in + (size_t)(r0 + r) * n + c0 + cc);
    tile[r][cc + 0] = v.x; tile[r][cc + 1] = v.y;
    tile[r][cc + 2] = v.z; tile[r][cc + 3] = v.w;
    ushort4 o;
    o.x = f2bf(v.x); o.y = f2bf(v.y); o.z = f2bf(v.z); o.w = f2bf(v.w);
    *(ushort4*)(outn + (size_t)(r0 + r) * n + c0 + cc) = o;
  }
  __syncthreads();
#pragma unroll
  for (int p = 0; p < 4; p++) {
    int r = cr + p * 16;  // output row = c0 + r
    ushort4 o;
    o.x = f2bf(tile[cc + 0][r]); o.y = f2bf(tile[cc + 1][r]);
    o.z = f2bf(tile[cc + 2][r]); o.w = f2bf(tile[cc + 3][r]);
    *(ushort4*)(outt + (size_t)(c0 + r) * n + r0 + cc) = o;
  }
}

// =====================================================================
// K1 (fused f32 conversion): pw_t[512 x 8192] = (concat(pre,cur) @ w)^T
// A = wt_t bf16 via global_load_lds; B = pre/cur f32 rows, converted
// in-register -> ds_write_b128. 64x128 tile, BK=32, 512 blocks.
// =====================================================================
__global__ __launch_bounds__(256) void k1_gemm(
    const ushort_t* __restrict__ wt_t, const float* __restrict__ pre,
    const float* __restrict__ cur, ushort_t* __restrict__ pw_t) {
  __shared__ __align__(16) ushort_t sA[64 * 32];
  __shared__ __align__(16) ushort_t sB[128 * 32];
  const int t = threadIdx.x;
  const int wave = t >> 6, lane = t & 63;
  const int lm = lane & 15, lq = lane >> 4;
  const int wr = wave >> 1, wc = wave & 1;
  const int bm = blockIdx.x & 7, bn = blockIdx.x >> 3;
  const int n0 = bn * 128;
  const ushort_t* A = wt_t + (size_t)bm * 64 * 512;
  const float* Bf = (n0 < 4096) ? (pre + (size_t)n0 * 512)
                                : (cur + (size_t)(n0 - 4096) * 512);
  ushort_t* C = pw_t + (size_t)bm * 64 * 8192 + n0;

  f32x4 acc[2][4] = {};
  const ushort_t* ga = A + (size_t)(t >> 2) * 512 + (t & 3) * 8;
  const float* gb = Bf + (size_t)(t >> 2) * 512 + (t & 3) * 8;
  ushort_t* sA0 = sA + wave * 512;
  ushort_t* sBw = sB + t * 8;  // = row(t>>2)*32 + (t&3)*8

  for (int k0 = 0; k0 < 512; k0 += 32) {
    async_cp16(ga + k0, sA0);  // A: 64x32 in one call
    float4 u0 = *(const float4*)(gb + k0);
    float4 u1 = *(const float4*)(gb + k0 + 4);
    float4 u2 = *(const float4*)(gb + k0 + (size_t)64 * 512);
    float4 u3 = *(const float4*)(gb + k0 + (size_t)64 * 512 + 4);
    short8 w0, w1;
    w0[0] = (short)f2bf(u0.x); w0[1] = (short)f2bf(u0.y);
    w0[2] = (short)f2bf(u0.z); w0[3] = (short)f2bf(u0.w);
    w0[4] = (short)f2bf(u1.x); w0[5] = (short)f2bf(u1.y);
    w0[6] = (short)f2bf(u1.z); w0[7] = (short)f2bf(u1.w);
    w1[0] = (short)f2bf(u2.x); w1[1] = (short)f2bf(u2.y);
    w1[2] = (short)f2bf(u2.z); w1[3] = (short)f2bf(u2.w);
    w1[4] = (short)f2bf(u3.x); w1[5] = (short)f2bf(u3.y);
    w1[6] = (short)f2bf(u3.z); w1[7] = (short)f2bf(u3.w);
    *(short8*)(sBw) = w0;
    *(short8*)(sBw + 2048) = w1;
    __syncthreads();

    short8 af[2], bf4[4];
#pragma unroll
    for (int i = 0; i < 2; i++)
      af[i] = *(const short8*)(sA + (wr * 32 + i * 16 + lm) * 32 + lq * 8);
#pragma unroll
    for (int i = 0; i < 4; i++)
      bf4[i] = *(const short8*)(sB + (wc * 64 + i * 16 + lm) * 32 + lq * 8);
#pragma unroll
    for (int mt = 0; mt < 2; mt++)
#pragma unroll
      for (int nt = 0; nt < 4; nt++)
        acc[mt][nt] = __builtin_amdgcn_mfma_f32_16x16x32_bf16(
            af[mt], bf4[nt], acc[mt][nt], 0, 0, 0);
    __syncthreads();
  }

#pragma unroll
  for (int mt = 0; mt < 2; mt++) {
    int rb = wr * 32 + mt * 16 + lq * 4;
#pragma unroll
    for (int nt = 0; nt < 4; nt++) {
      int c = wc * 64 + nt * 16 + lm;
#pragma unroll
      for (int r = 0; r < 4; r++)
        C[(size_t)(rb + r) * 8192 + c] = f2bf(acc[mt][nt][r]);
    }
  }
}

// =====================================================================
// K2 fused: half0 pre_h = adj @ cur_w ; half1 cur_h = adj^T @ pre_w
// 128x64 tiles, BK=64 (half the barriers), 512 blocks (2/CU), XCD swizzle.
// =====================================================================
__global__ __launch_bounds__(256) void k2_gemm(
    const ushort_t* __restrict__ adj, const ushort_t* __restrict__ adj_t,
    const ushort_t* __restrict__ pw_t, ushort_t* __restrict__ pn) {
  __shared__ __align__(16) ushort_t sA[128 * 64];
  __shared__ __align__(16) ushort_t sB[64 * 64];
  const int b = blockIdx.x;
  const int half = b >> 8, bb = b & 255;
  const int bn = (bb >> 3) & 7;
  const int bm = (bb & 7) | ((bb >> 6) << 3);
  const ushort_t* A = (half ? adj_t : adj) + (size_t)bm * 128 * 4096;
  const ushort_t* B = pw_t + (size_t)bn * 64 * 8192 + (half ? 0 : 4096);
  ushort_t* C = pn + (half ? (size_t)4096 * 512 : 0) +
                (size_t)bm * 128 * 512 + bn * 64;
  gemm_core<128, 64, 64, 1>(A, 4096, B, 8192, 4096, sA, sB, C, nullptr,
                            nullptr, 512, nullptr, nullptr);
}

// =====================================================================
// invnorm: invn[row] = 1 / max(||pn[row]||, 1e-8), one wave per row
// =====================================================================
__global__ __launch_bounds__(256) void invnorm_kernel(
    const ushort_t* __restrict__ pn, float* __restrict__ invn) {
  const int t = threadIdx.x;
  const int wave = t >> 6, lane = t & 63;
  const size_t row = (size_t)blockIdx.x * 4 + wave;
  const ushort_t* p = pn + row * 512 + lane * 8;
  short8 v = *(const short8*)p;
  float s = 0.f;
#pragma unroll
  for (int i = 0; i < 8; i++) {
    float f = bf2f((ushort_t)v[i]);
    s += f * f;
  }
#pragma unroll
  for (int off = 32; off > 0; off >>= 1) s += __shfl_xor(s, off, 64);
  if (lane == 0) invn[row] = 1.0f / fmaxf(sqrtf(s), 1e-8f);
}

// =====================================================================
// K3: cos = (pre_h @ cur_h^T) * inv_i * inv_j, tan, dual f32 store.
// 128x128, BK=32, 1024 blocks.
// =====================================================================
__global__ __launch_bounds__(256) void k3_gemm(
    const ushort_t* __restrict__ pn, const float* __restrict__ invn,
    float* __restrict__ out) {
  __shared__ __align__(16) ushort_t sA[128 * 32];
  __shared__ __align__(16) ushort_t sB[128 * 32];
  const int bm = blockIdx.x & 31, bn = blockIdx.x >> 5;
  const ushort_t* A = pn + (size_t)bm * 128 * 512;
  const ushort_t* B = pn + (size_t)4096 * 512 + (size_t)bn * 128 * 512;
  float* C0 = out + (size_t)bm * 128 * 4096 + bn * 128;
  gemm_core<128, 128, 32, 2>(A, 512, B, 512, 512, sA, sB, nullptr, C0,
                             C0 + (size_t)4096 * 4096, 4096,
                             invn + bm * 128, invn + 4096 + bn * 128);
}

// =====================================================================
extern "C" void kernel_launch(void* const* d_in, const int* in_sizes, int n_in,
                              void* d_out, int out_size, void* d_ws,
                              size_t ws_size, hipStream_t stream) {
  const float* pre = (const float*)d_in[0];   // [4096,512] f32
  const float* cur = (const float*)d_in[1];   // [4096,512] f32
  const float* adj = (const float*)d_in[2];   // [4096,4096] f32
  const float* wt  = (const float*)d_in[3];   // [512,512] f32
  float* out = (float*)d_out;                 // 2 x [4096,4096] f32

  // workspace layout (~85 MB)
  ushort_t* adj_bf = (ushort_t*)d_ws;                       // 4096*4096
  ushort_t* adj_t  = adj_bf + (size_t)4096 * 4096;          // 4096*4096
  ushort_t* pw_t   = adj_t + (size_t)4096 * 4096;           // 512*8192
  ushort_t* pn     = pw_t + (size_t)512 * 8192;             // 8192*512
  ushort_t* wt_t   = pn + (size_t)8192 * 512;               // 512*512
  ushort_t* wt_bf  = wt_t + (size_t)512 * 512;              // 512*512 (dummy)
  float*    invn   = (float*)(wt_bf + (size_t)512 * 512);   // 8192 f32

  convT<<<dim3(64, 64), 256, 0, stream>>>(adj, adj_bf, adj_t, 4096);
  convT<<<dim3(8, 8), 256, 0, stream>>>(wt, wt_bf, wt_t, 512);
  k1_gemm<<<512, 256, 0, stream>>>(wt_t, pre, cur, pw_t);
  k2_gemm<<<512, 256, 0, stream>>>(adj_bf, adj_t, pw_t, pn);
  invnorm_kernel<<<2048, 256, 0, stream>>>(pn, invn);
  k3_gemm<<<1024, 256, 0, stream>>>(pn, invn, out);
}